// Round 6
// baseline (146.178 us; speedup 1.0000x reference)
//
#include <hip/hip_runtime.h>
#include <hip/hip_bf16.h>
#include <stdint.h>

#define P    300
#define HID  128
#define NG   1000
#define NTL  19          // 16-node tiles (304 rows, 300 valid)

typedef __attribute__((ext_vector_type(8))) short bf16x8;
typedef __attribute__((ext_vector_type(4))) short bf16x4;
typedef __attribute__((ext_vector_type(4))) float f32x4;

// Swizzled bf16 W^T. Slot fkey holds weights for column perm(fkey):
// W2 (pass1): perm(fkey) = u*32 + 2*(fkey&15) + ((fkey>>4)&1), u=fkey>>5.
// W3 (pass2): natural. chunk(fkey,kc) at slot fkey*16 + (kc ^ (fkey&15)).
__device__ short g_wsw[2 * HID * HID];

__device__ __forceinline__ short f2bf(float f) {
    union { float f; uint32_t u; } v; v.f = f;
    uint32_t r = v.u + 0x7fffu + ((v.u >> 16) & 1u);   // RNE
    return (short)(r >> 16);
}
__device__ __forceinline__ uint32_t pkbf2(float a, float b) {   // low=a, high=b
    union { __hip_bfloat162 h; uint32_t u; } cv;
    cv.h = __float22bfloat162_rn(float2{a, b});
    return cv.u;
}

// K=16 bf16 MFMA used as a cross-lane "selector": A is a constant 0/1
// matrix, B is a bf16-packed G-tile, C accumulates neighbor rows in f32.
// Layout match: C-frag of 16x16x32 (row=4q+reg, col=lm) == B-frag of
// 16x16x16 (k=4q+j, col=lm) -> pack is 2 pkbf2, NO shuffles.
__device__ __forceinline__ f32x4 mfma16(bf16x4 a, bf16x4 b, f32x4 c) {
#if __has_builtin(__builtin_amdgcn_mfma_f32_16x16x16bf16_1k)
    return __builtin_amdgcn_mfma_f32_16x16x16bf16_1k(a, b, c, 0, 0, 0);
#else
    asm("v_mfma_f32_16x16x16_bf16 %0, %1, %2, %0" : "+v"(c) : "v"(a), "v"(b));
    return c;
#endif
}

__global__ __launch_bounds__(256) void k_prep(const float* __restrict__ W2,
                                              const float* __restrict__ W3) {
    int b = blockIdx.x;                       // 16 blocks
    const bool perm = (b < 8);
    const float* W = perm ? W2 : W3;
    short* dst = g_wsw + (perm ? 0 : HID * HID);
    int t    = (b & 7) * 256 + threadIdx.x;   // 0..2047 chunks
    int fkey = t >> 4;
    int kc   = t & 15;
    int fsrc;
    if (perm) {
        int u = fkey >> 5, ft = (fkey >> 4) & 1, l = fkey & 15;
        fsrc = u * 32 + 2 * l + ft;
    } else fsrc = fkey;
    bf16x8 o;
    #pragma unroll
    for (int j = 0; j < 8; ++j)
        o[j] = f2bf(W[(kc * 8 + j) * HID + fsrc]);
    *(bf16x8*)&dst[(fkey * 16 + (kc ^ (fkey & 15))) * 8] = o;
}

// One GCN layer over one graph in LDS; 4 waves, each owning 2 ft-tiles.
// 3-phase / 2-barrier skeleton (race-proof: phase B reads {9..1}, stores
// {10..18,0}; disjoint). Neighbor exchange via K=16 selector MFMAs on
// bf16-packed G tiles (bq) -- no ds_bpermute chains. Numerics identical
// to round 0/4: center terms f32 in-lane, neighbor terms bf16 (same
// pkbf2 RNE); verified round 5 (absmax unchanged).
//   Sb: in-tile quad boundaries (row 4i   <- row 4i-1,
//                                row 4i+3 <- row 4i+4)
//   Sp: row0  <- row15 of tile T-1     Sn: row15 <- row0 of tile T+1
//   Swa (T==18): row11 <- row0 of tile 0  (node299.next = node0)
//   Swb (T==0):  row0  <- row11 of tile18 (node0.prev  = node299)
template<int POOL>
__device__ __forceinline__ void run_pass(short* __restrict__ buf,
                                         const short* __restrict__ wbase,
                                         const float* __restrict__ bias,
                                         float* __restrict__ pool, int tid) {
    const int lane = tid & 63, wv = tid >> 6, q = lane >> 4, lm = lane & 15;
    const int ftg0 = wv * 2;
    bf16x8 wf[2][4];
    #pragma unroll
    for (int ft = 0; ft < 2; ++ft) {
        int fkey = (ftg0 + ft) * 16 + lm;
        #pragma unroll
        for (int kk = 0; kk < 4; ++kk)
            wf[ft][kk] = *(const bf16x8*)&wbase[(fkey * 16 + ((4 * kk + q) ^ lm)) * 8];
    }
    float biaf[2];
    #pragma unroll
    for (int ft = 0; ft < 2; ++ft)
        biaf[ft] = POOL ? bias[(ftg0 + ft) * 16 + lm] : bias[wv * 32 + 2 * lm + ft];
    const int fpair = wv * 32 + 2 * lm;       // even physical feature (pass1)
    const int kcs = fpair >> 3, offs = fpair & 7;

    // constant selector A-fragments: A[m=lm][k=4q+j], entries bf16 1.0
    const short ONE = (short)0x3F80;
    bf16x4 Sb = {0, 0, 0, 0}, Sp = {0, 0, 0, 0}, Sn = {0, 0, 0, 0},
           Swa = {0, 0, 0, 0}, Swb = {0, 0, 0, 0};
    #pragma unroll
    for (int j = 0; j < 4; ++j) {
        const int k = 4 * q + j;
        if (((lm & 3) == 0 && k == lm - 1) || ((lm & 3) == 3 && k == lm + 1))
            Sb[j] = ONE;
        if (lm == 0  && k == 15) Sp[j]  = ONE;
        if (lm == 15 && k == 0 ) Sn[j]  = ONE;
        if (lm == 11 && k == 0 ) Swa[j] = ONE;
        if (lm == 0  && k == 11) Swb[j] = ONE;
    }

    float psum[2] = {0.f, 0.f};
    bf16x4 bq[NTL][2];     // bf16-packed G tiles (B-frags), static idx only

    auto mfma_tile = [&](int t, f32x4* G) {
        const short* tb = buf + t * 2048;
        G[0] = f32x4{0.f, 0.f, 0.f, 0.f};
        G[1] = f32x4{0.f, 0.f, 0.f, 0.f};
        #pragma unroll
        for (int kk = 0; kk < 4; ++kk) {
            bf16x8 af = *(const bf16x8*)&tb[(lm * 16 + ((4 * kk + q) ^ lm)) * 8];
            G[0] = __builtin_amdgcn_mfma_f32_16x16x32_bf16(af, wf[0][kk], G[0], 0, 0, 0);
            G[1] = __builtin_amdgcn_mfma_f32_16x16x32_bf16(af, wf[1][kk], G[1], 0, 0, 0);
        }
    };
    auto store_rows = [&](int T, float (&o)[2][4]) {
        #pragma unroll
        for (int i = 0; i < 4; ++i) {
            int node = T * 16 + q * 4 + i;
            *(uint32_t*)&buf[(node * 16 + (kcs ^ (node & 15))) * 8 + offs] =
                pkbf2(o[0][i], o[1][i]);
        }
    };
    auto accum = [&](float (&o)[2][4]) {
        #pragma unroll
        for (int ft = 0; ft < 2; ++ft)
            psum[ft] += o[ft][0] + o[ft][1] + o[ft][2] + o[ft][3];
    };

    // epilogue of tile: E = f32 centers; bT/bP/bN = bq[T]/bq[T-1]/bq[T+1];
    // wrap: 0 none, 1 = tile18 (+Swa x bq[0]), 2 = tile0 (+Swb x bq[18]).
    auto epi = [&](const f32x4 (&E)[2], const bf16x4 (&bT)[2],
                   const bf16x4 (&bP)[2], const bf16x4 (&bN)[2],
                   int wrap, float (&o)[2][4]) {
        #pragma unroll
        for (int ft = 0; ft < 2; ++ft) {
            f32x4 C = {0.f, 0.f, 0.f, 0.f};
            C = mfma16(Sb, bT[ft], C);
            C = mfma16(Sp, bP[ft], C);
            C = mfma16(Sn, bN[ft], C);
            if (wrap == 1) C = mfma16(Swa, bq[0][ft], C);
            if (wrap == 2) C = mfma16(Swb, bq[18][ft], C);
            const float s0 = E[ft][0] + E[ft][1];
            const float s2 = E[ft][2] + E[ft][3];
            float t0 = C[0] + s0;            // prev + G0 + G1
            float t1 = s0 + E[ft][2];        // G0 + G1 + G2
            float t2 = E[ft][1] + s2;        // G1 + G2 + G3
            float t3 = s2 + C[3];            // G2 + G3 + next
            float v0 = fmaf(t0, 1.f / 3.f, biaf[ft]);
            float v1 = fmaf(t1, 1.f / 3.f, biaf[ft]);
            float v2 = fmaf(t2, 1.f / 3.f, biaf[ft]);
            float v3 = fmaf(t3, 1.f / 3.f, biaf[ft]);
            o[ft][0] = v0 > 0.f ? v0 : 0.f;
            o[ft][1] = v1 > 0.f ? v1 : 0.f;
            o[ft][2] = v2 > 0.f ? v2 : 0.f;
            o[ft][3] = v3 > 0.f ? v3 : 0.f;
        }
    };

    f32x4 GH[10][2];   // GH[k] = G[10+k] for k<9; GH[9] = G[0]
    f32x4 GL[9][2];    // GL[i] = G[9-i]

    // ---- phase A: MFMA tiles 10..18 and 0; pack bq (reads only) ----
    #pragma unroll
    for (int k = 0; k < 9; ++k) {
        mfma_tile(10 + k, GH[k]);
        #pragma unroll
        for (int ft = 0; ft < 2; ++ft) {
            union { bf16x4 v; uint32_t u[2]; } pk;
            pk.u[0] = pkbf2(GH[k][ft][0], GH[k][ft][1]);
            pk.u[1] = pkbf2(GH[k][ft][2], GH[k][ft][3]);
            bq[10 + k][ft] = pk.v;
        }
    }
    mfma_tile(0, GH[9]);
    #pragma unroll
    for (int ft = 0; ft < 2; ++ft) {
        union { bf16x4 v; uint32_t u[2]; } pk;
        pk.u[0] = pkbf2(GH[9][ft][0], GH[9][ft][1]);
        pk.u[1] = pkbf2(GH[9][ft][2], GH[9][ft][3]);
        bq[0][ft] = pk.v;
    }
    if (!POOL) __syncthreads();

    // ---- phase B: MFMA 9..1 interleaved with epi/store of 10..18, 0 ----
    #pragma unroll
    for (int i = 0; i < 9; ++i) {
        mfma_tile(9 - i, GL[i]);
        #pragma unroll
        for (int ft = 0; ft < 2; ++ft) {
            union { bf16x4 v; uint32_t u[2]; } pk;
            pk.u[0] = pkbf2(GL[i][ft][0], GL[i][ft][1]);
            pk.u[1] = pkbf2(GL[i][ft][2], GL[i][ft][3]);
            bq[9 - i][ft] = pk.v;
        }
        if (i < 8) {
            float o[2][4];
            epi(GH[i], bq[10 + i], bq[9 + i], bq[11 + i], 0, o);
            if (POOL) accum(o); else store_rows(10 + i, o);
        } else {
            float o18[2][4];   // rows 300..303 invalid: q==3 skipped
            epi(GH[8], bq[18], bq[17], bq[0], 1, o18);
            if (q < 3) { if (POOL) accum(o18); else store_rows(18, o18); }
            float o0[2][4];
            epi(GH[9], bq[0], bq[18], bq[1], 2, o0);
            if (POOL) accum(o0); else store_rows(0, o0);
        }
    }
    if (!POOL) __syncthreads();

    // ---- phase C: epi/store tiles 1..9 (stores only) ----
    #pragma unroll
    for (int T = 1; T <= 9; ++T) {
        float o[2][4];
        epi(GL[9 - T], bq[T], bq[T - 1], bq[T + 1], 0, o);
        if (POOL) accum(o); else store_rows(T, o);
    }

    if (POOL) {
        #pragma unroll
        for (int ft = 0; ft < 2; ++ft) {
            psum[ft] += __shfl_xor(psum[ft], 16, 64);
            psum[ft] += __shfl_xor(psum[ft], 32, 64);
        }
        if (q == 0) {
            pool[ftg0 * 16 + lm]      = psum[0];
            pool[ftg0 * 16 + 16 + lm] = psum[1];
        }
    }
}

// One block (256 thr, 4 waves) per graph. LDS 80384 B (HW-proven 2/CU).
// launch_bounds 2nd-arg empirical cap model: (512,4)->64, (256,2)->128,
// i.e. cap = 256/arg2. Round 5's (256,2) capped the ~230-reg live set at
// 128 -> ~29 MB/dispatch scratch spill (WRITE_SIZE 20.6 MB). (256,1)
// gives cap 256: fits the live set, and <=256 VGPR still allows the
// 2 waves/SIMD the LDS limit dictates -- occupancy unchanged.
__global__ __launch_bounds__(256, 1) void k_graph(
        const float* __restrict__ x,
        const float* __restrict__ W1,  const float* __restrict__ b1,
        const float* __restrict__ b2v, const float* __restrict__ b3v,
        const float* __restrict__ fw1, const float* __restrict__ fb1,
        const float* __restrict__ fw2, const float* __restrict__ fb2,
        float* __restrict__ out) {
    __shared__ __align__(16) short buf[304 * HID];   // 77824 B, chunk-swizzled
    __shared__ __align__(16) float scr[640];         // 2560 B -> total 80384
    float* xs    = scr;          // 600 (layer-1 only)
    float* pool  = scr;          // 128
    float* parts = scr + 128;    // 256
    float* s1    = scr + 384;    // 128

    const int g = blockIdx.x, tid = threadIdx.x;

    if (tid < 150) *(float4*)&xs[tid * 4] = *(const float4*)&x[g * 600 + tid * 4];
    __syncthreads();

    // ---- layer 1: buf <- relu(avg3(x) @ W1 + b1); rows 300..303 zeroed ----
    {
        const int kc1 = tid & 15;
        const int n0  = tid >> 4;
        float w1x[8], w1y[8], b1v[8];
        #pragma unroll
        for (int j = 0; j < 8; ++j) {
            w1x[j] = W1[kc1 * 8 + j];
            w1y[j] = W1[HID + kc1 * 8 + j];
            b1v[j] = b1[kc1 * 8 + j];
        }
        #pragma unroll
        for (int it = 0; it < NTL; ++it) {
            int node = it * 16 + n0;
            uint32_t w[4] = {0u, 0u, 0u, 0u};
            if (node < P) {
                int prev = (node == 0)     ? P - 1 : node - 1;
                int next = (node == P - 1) ? 0     : node + 1;
                float2 xp = *(const float2*)&xs[2 * prev];
                float2 xc = *(const float2*)&xs[2 * node];
                float2 xn = *(const float2*)&xs[2 * next];
                float ax = (xp.x + xc.x + xn.x) * (1.f / 3.f);
                float ay = (xp.y + xc.y + xn.y) * (1.f / 3.f);
                #pragma unroll
                for (int jj = 0; jj < 4; ++jj) {
                    float va = ax * w1x[2*jj]   + ay * w1y[2*jj]   + b1v[2*jj];
                    float vb = ax * w1x[2*jj+1] + ay * w1y[2*jj+1] + b1v[2*jj+1];
                    va = va > 0.f ? va : 0.f;
                    vb = vb > 0.f ? vb : 0.f;
                    w[jj] = pkbf2(va, vb);
                }
            }
            *(uint4*)&buf[(node * 16 + (kc1 ^ (node & 15))) * 8] =
                uint4{w[0], w[1], w[2], w[3]};
        }
    }
    __syncthreads();

    run_pass<0>(buf, g_wsw,             b2v, pool, tid);   // h1 -> h2 in place
    __syncthreads();
    run_pass<1>(buf, g_wsw + HID * HID, b3v, pool, tid);   // h2 -> pooled sums
    __syncthreads();

    // ---- FC head ----
    {
        int f = tid & 127, half = tid >> 7;
        float p = 0.f;
        const float* fw1c = fw1 + f;
        #pragma unroll 4
        for (int k = half * 64; k < half * 64 + 64; ++k)
            p += pool[k] * fw1c[k * 128];
        parts[half * 128 + f] = p;
    }
    __syncthreads();
    if (tid < 128) {
        float o1 = fb1[tid] + (parts[tid] + parts[128 + tid]) * (1.0f / 300.0f);
        s1[tid] = o1 > 0.f ? o1 : 0.f;
    }
    __syncthreads();
    if (tid < 128) {
        int o = tid >> 6, ln = tid & 63;
        float v = s1[ln] * fw2[ln * 2 + o] + s1[ln + 64] * fw2[(ln + 64) * 2 + o];
        #pragma unroll
        for (int off = 1; off <= 32; off <<= 1)
            v += __shfl_xor(v, off, 64);
        if (ln == 0) out[g * 2 + o] = v + fb2[o];
    }
}

extern "C" void kernel_launch(void* const* d_in, const int* in_sizes, int n_in,
                              void* d_out, int out_size, void* d_ws, size_t ws_size,
                              hipStream_t stream) {
    const float* x   = (const float*)d_in[0];
    const float* W1  = (const float*)d_in[3];
    const float* b1  = (const float*)d_in[4];
    const float* W2  = (const float*)d_in[5];
    const float* b2  = (const float*)d_in[6];
    const float* W3  = (const float*)d_in[7];
    const float* b3  = (const float*)d_in[8];
    const float* fw1 = (const float*)d_in[9];
    const float* fb1 = (const float*)d_in[10];
    const float* fw2 = (const float*)d_in[11];
    const float* fb2 = (const float*)d_in[12];
    float* out = (float*)d_out;

    k_prep <<<dim3(16), dim3(256), 0, stream>>>(W2, W3);
    k_graph<<<dim3(NG), dim3(256), 0, stream>>>(x, W1, b1, b2, b3,
                                                fw1, fb1, fw2, fb2, out);
}

// Round 7
// 130.068 us; speedup vs baseline: 1.1239x; 1.1239x over previous
//
#include <hip/hip_runtime.h>
#include <hip/hip_bf16.h>
#include <stdint.h>

#define P    300
#define HID  128
#define NG   1000
#define NTL  19          // 16-node tiles (304 rows, 300 valid)

typedef __attribute__((ext_vector_type(8))) short bf16x8;
typedef __attribute__((ext_vector_type(4))) short bf16x4;
typedef __attribute__((ext_vector_type(4))) float f32x4;

// Swizzled bf16 W^T. Slot fkey holds weights for column perm(fkey):
// W2 (pass1): perm(fkey) = u*32 + 2*(fkey&15) + ((fkey>>4)&1), u=fkey>>5.
// W3 (pass2): natural. chunk(fkey,kc) at slot fkey*16 + (kc ^ (fkey&15)).
__device__ short g_wsw[2 * HID * HID];

__device__ __forceinline__ short f2bf(float f) {
    union { float f; uint32_t u; } v; v.f = f;
    uint32_t r = v.u + 0x7fffu + ((v.u >> 16) & 1u);   // RNE
    return (short)(r >> 16);
}
__device__ __forceinline__ uint32_t pkbf2(float a, float b) {   // low=a, high=b
    union { __hip_bfloat162 h; uint32_t u; } cv;
    cv.h = __float22bfloat162_rn(float2{a, b});
    return cv.u;
}

// K=16 bf16 MFMA used as a cross-lane "selector": A is a constant 0/1
// matrix, B is a bf16-packed G-tile, C accumulates neighbor rows in f32.
// Layout match: C-frag of 16x16x32 (row=4q+reg, col=lm) == B-frag of
// 16x16x16 (k=4q+j, col=lm) -> pack is 2 pkbf2, NO shuffles.
__device__ __forceinline__ f32x4 mfma16(bf16x4 a, bf16x4 b, f32x4 c) {
#if __has_builtin(__builtin_amdgcn_mfma_f32_16x16x16bf16_1k)
    return __builtin_amdgcn_mfma_f32_16x16x16bf16_1k(a, b, c, 0, 0, 0);
#else
    asm("v_mfma_f32_16x16x16_bf16 %0, %1, %2, %0" : "+v"(c) : "v"(a), "v"(b));
    return c;
#endif
}

__global__ __launch_bounds__(256) void k_prep(const float* __restrict__ W2,
                                              const float* __restrict__ W3) {
    int b = blockIdx.x;                       // 16 blocks
    const bool perm = (b < 8);
    const float* W = perm ? W2 : W3;
    short* dst = g_wsw + (perm ? 0 : HID * HID);
    int t    = (b & 7) * 256 + threadIdx.x;   // 0..2047 chunks
    int fkey = t >> 4;
    int kc   = t & 15;
    int fsrc;
    if (perm) {
        int u = fkey >> 5, ft = (fkey >> 4) & 1, l = fkey & 15;
        fsrc = u * 32 + 2 * l + ft;
    } else fsrc = fkey;
    bf16x8 o;
    #pragma unroll
    for (int j = 0; j < 8; ++j)
        o[j] = f2bf(W[(kc * 8 + j) * HID + fsrc]);
    *(bf16x8*)&dst[(fkey * 16 + (kc ^ (fkey & 15))) * 8] = o;
}

// One GCN layer over one graph in LDS; 4 waves, each owning 2 ft-tiles.
// ROLLING-WINDOW schedule (round-0 skeleton, ~115-reg live set so 2
// blocks/CU co-reside) + selector-MFMA neighbor exchange (round-5/6
// epilogue, 27% faster per block than shuffles):
//   loop j=1..9: read tiles 2j-1, 2j -> Ga,Gb (+pack bqC,bqD); barrier;
//   epi/store tile 2j-2 (Gp, bqA,bqB,bqC), epi/store tile 2j-1
//   (Ga, bqB,bqC,bqD); rotate. Tiles 0 and 18 deferred to tail
//   (persist G0 centers, bq0, bq1). Stores {2j-2,2j-1} vs reads
//   {2j+1,2j+2}: disjoint -> race-free under the per-iteration barrier.
// Selectors (verified round 5, absmax unchanged):
//   Sb: row 4i <- row 4i-1, row 4i+3 <- row 4i+4 (in-tile)
//   Sp: row0 <- row15 of bP      Sn: row15 <- row0 of bN
//   Swa (tile18): row11 <- row0 of tile0 (node299.next = node0)
//   Swb (tile0):  row0 <- row11 of tile18 (node0.prev = node299;
//        Sp x bq18 adds row15 = node303 = 0 -- rows 300..303 stay zero)
template<int POOL>
__device__ __forceinline__ void run_pass(short* __restrict__ buf,
                                         const short* __restrict__ wbase,
                                         const float* __restrict__ bias,
                                         float* __restrict__ pool, int tid) {
    const int lane = tid & 63, wv = tid >> 6, q = lane >> 4, lm = lane & 15;
    const int ftg0 = wv * 2;
    bf16x8 wf[2][4];
    #pragma unroll
    for (int ft = 0; ft < 2; ++ft) {
        int fkey = (ftg0 + ft) * 16 + lm;
        #pragma unroll
        for (int kk = 0; kk < 4; ++kk)
            wf[ft][kk] = *(const bf16x8*)&wbase[(fkey * 16 + ((4 * kk + q) ^ lm)) * 8];
    }
    float biaf[2];
    #pragma unroll
    for (int ft = 0; ft < 2; ++ft)
        biaf[ft] = POOL ? bias[(ftg0 + ft) * 16 + lm] : bias[wv * 32 + 2 * lm + ft];
    const int fpair = wv * 32 + 2 * lm;       // even physical feature (pass1)
    const int kcs = fpair >> 3, offs = fpair & 7;

    // constant selector A-fragments: A[m=lm][k=4q+j], entries bf16 1.0
    const short ONE = (short)0x3F80;
    bf16x4 Sb = {0, 0, 0, 0}, Sp = {0, 0, 0, 0}, Sn = {0, 0, 0, 0},
           Swa = {0, 0, 0, 0}, Swb = {0, 0, 0, 0};
    #pragma unroll
    for (int j = 0; j < 4; ++j) {
        const int k = 4 * q + j;
        if (((lm & 3) == 0 && k == lm - 1) || ((lm & 3) == 3 && k == lm + 1))
            Sb[j] = ONE;
        if (lm == 0  && k == 15) Sp[j]  = ONE;
        if (lm == 15 && k == 0 ) Sn[j]  = ONE;
        if (lm == 11 && k == 0 ) Swa[j] = ONE;
        if (lm == 0  && k == 11) Swb[j] = ONE;
    }

    float psum[2] = {0.f, 0.f};

    auto mfma_tile = [&](int t, f32x4 (&G)[2]) {
        const short* tb = buf + t * 2048;
        G[0] = f32x4{0.f, 0.f, 0.f, 0.f};
        G[1] = f32x4{0.f, 0.f, 0.f, 0.f};
        #pragma unroll
        for (int kk = 0; kk < 4; ++kk) {
            bf16x8 af = *(const bf16x8*)&tb[(lm * 16 + ((4 * kk + q) ^ lm)) * 8];
            G[0] = __builtin_amdgcn_mfma_f32_16x16x32_bf16(af, wf[0][kk], G[0], 0, 0, 0);
            G[1] = __builtin_amdgcn_mfma_f32_16x16x32_bf16(af, wf[1][kk], G[1], 0, 0, 0);
        }
    };
    auto pack = [&](const f32x4 (&G)[2], bf16x4 (&d)[2]) {
        #pragma unroll
        for (int ft = 0; ft < 2; ++ft) {
            union { bf16x4 v; uint32_t u[2]; } pk;
            pk.u[0] = pkbf2(G[ft][0], G[ft][1]);
            pk.u[1] = pkbf2(G[ft][2], G[ft][3]);
            d[ft] = pk.v;
        }
    };
    auto store_rows = [&](int T, float (&o)[2][4]) {
        #pragma unroll
        for (int i = 0; i < 4; ++i) {
            int node = T * 16 + q * 4 + i;
            *(uint32_t*)&buf[(node * 16 + (kcs ^ (node & 15))) * 8 + offs] =
                pkbf2(o[0][i], o[1][i]);
        }
    };
    auto accum = [&](float (&o)[2][4]) {
        #pragma unroll
        for (int ft = 0; ft < 2; ++ft)
            psum[ft] += o[ft][0] + o[ft][1] + o[ft][2] + o[ft][3];
    };

    // epilogue: E f32 centers; bT/bP/bN packed self/prev/next; wrap:
    // 0 none, 1 tile18 (+Swa x bW), 2 tile0 (+Swb x bW).
    auto epi = [&](const f32x4 (&E)[2], const bf16x4 (&bT)[2],
                   const bf16x4 (&bP)[2], const bf16x4 (&bN)[2],
                   int wrap, const bf16x4 (&bW)[2], float (&o)[2][4]) {
        #pragma unroll
        for (int ft = 0; ft < 2; ++ft) {
            f32x4 C = {0.f, 0.f, 0.f, 0.f};
            C = mfma16(Sb, bT[ft], C);
            C = mfma16(Sp, bP[ft], C);
            C = mfma16(Sn, bN[ft], C);
            if (wrap == 1) C = mfma16(Swa, bW[ft], C);
            if (wrap == 2) C = mfma16(Swb, bW[ft], C);
            const float s0 = E[ft][0] + E[ft][1];
            const float s2 = E[ft][2] + E[ft][3];
            float t0 = C[0] + s0;            // prev + G0 + G1
            float t1 = s0 + E[ft][2];        // G0 + G1 + G2
            float t2 = E[ft][1] + s2;        // G1 + G2 + G3
            float t3 = s2 + C[3];            // G2 + G3 + next
            float v0 = fmaf(t0, 1.f / 3.f, biaf[ft]);
            float v1 = fmaf(t1, 1.f / 3.f, biaf[ft]);
            float v2 = fmaf(t2, 1.f / 3.f, biaf[ft]);
            float v3 = fmaf(t3, 1.f / 3.f, biaf[ft]);
            o[ft][0] = v0 > 0.f ? v0 : 0.f;
            o[ft][1] = v1 > 0.f ? v1 : 0.f;
            o[ft][2] = v2 > 0.f ? v2 : 0.f;
            o[ft][3] = v3 > 0.f ? v3 : 0.f;
        }
    };

    f32x4 G0c[2], Gp[2], Ga[2], Gb[2];
    bf16x4 bq0[2], bq1[2], bqA[2], bqB[2], bqC[2], bqD[2];

    // prologue: tile 0 (persist centers + pack; epilogued at tail)
    mfma_tile(0, G0c);
    pack(G0c, bq0);
    bqB[0] = bq0[0]; bqB[1] = bq0[1];     // entering j=1: bqB = bq[0]
    bqA[0] = bq0[0]; bqA[1] = bq0[1];     // unused at j=1 (init for safety)
    Gp[0] = G0c[0]; Gp[1] = G0c[1];       // unused at j=1

    for (int j = 1; j <= 9; ++j) {
        mfma_tile(2 * j - 1, Ga); pack(Ga, bqC);
        mfma_tile(2 * j,     Gb); pack(Gb, bqD);
        if (j == 1) { bq1[0] = bqC[0]; bq1[1] = bqC[1]; }   // persist bq[1]
        if (!POOL) __syncthreads();       // all waves read tiles <= 2j
        if (j > 1) {                      // tile 2j-2 (tile 0 deferred)
            float o[2][4];
            epi(Gp, bqB, bqA, bqC, 0, bq0, o);
            if (POOL) accum(o); else store_rows(2 * j - 2, o);
        }
        {                                 // tile 2j-1
            float o[2][4];
            epi(Ga, bqC, bqB, bqD, 0, bq0, o);
            if (POOL) accum(o); else store_rows(2 * j - 1, o);
        }
        Gp[0] = Gb[0]; Gp[1] = Gb[1];
        bqA[0] = bqC[0]; bqA[1] = bqC[1];
        bqB[0] = bqD[0]; bqB[1] = bqD[1];
    }

    // tail (all reads done): Gp = G[18], bqA = bq[17], bqB = bq[18]
    {
        float o18[2][4];   // rows 300..303 invalid: q==3 skipped
        epi(Gp, bqB, bqA, bq0, 1, bq0, o18);
        if (q < 3) { if (POOL) accum(o18); else store_rows(18, o18); }
        float o0[2][4];    // Sp x bq18 row15 = node303 = 0; Swb adds node299
        epi(G0c, bq0, bqB, bq1, 2, bqB, o0);
        if (POOL) accum(o0); else store_rows(0, o0);
    }

    if (POOL) {
        #pragma unroll
        for (int ft = 0; ft < 2; ++ft) {
            psum[ft] += __shfl_xor(psum[ft], 16, 64);
            psum[ft] += __shfl_xor(psum[ft], 32, 64);
        }
        if (q == 0) {
            pool[ftg0 * 16 + lm]      = psum[0];
            pool[ftg0 * 16 + 16 + lm] = psum[1];
        }
    }
}

// One block (256 thr, 4 waves) per graph. LDS 80384 B (HW-proven 2/CU).
// Resource model (r0-r6 evidence): 2 blocks/CU needs total regs
// (VGPR+AGPR, unified file) <= ~256/wave AND LDS <= 80384. Round 6's
// 19-tile-resident schedule hit 180+ -> 1 block/CU; this rolling-window
// version targets ~115-130 live. (256,1): allocator takes what it needs.
__global__ __launch_bounds__(256, 1) void k_graph(
        const float* __restrict__ x,
        const float* __restrict__ W1,  const float* __restrict__ b1,
        const float* __restrict__ b2v, const float* __restrict__ b3v,
        const float* __restrict__ fw1, const float* __restrict__ fb1,
        const float* __restrict__ fw2, const float* __restrict__ fb2,
        float* __restrict__ out) {
    __shared__ __align__(16) short buf[304 * HID];   // 77824 B, chunk-swizzled
    __shared__ __align__(16) float scr[640];         // 2560 B -> total 80384
    float* xs    = scr;          // 600 (layer-1 only)
    float* pool  = scr;          // 128
    float* parts = scr + 128;    // 256
    float* s1    = scr + 384;    // 128

    const int g = blockIdx.x, tid = threadIdx.x;

    if (tid < 150) *(float4*)&xs[tid * 4] = *(const float4*)&x[g * 600 + tid * 4];
    __syncthreads();

    // ---- layer 1: buf <- relu(avg3(x) @ W1 + b1); rows 300..303 zeroed ----
    {
        const int kc1 = tid & 15;
        const int n0  = tid >> 4;
        float w1x[8], w1y[8], b1v[8];
        #pragma unroll
        for (int j = 0; j < 8; ++j) {
            w1x[j] = W1[kc1 * 8 + j];
            w1y[j] = W1[HID + kc1 * 8 + j];
            b1v[j] = b1[kc1 * 8 + j];
        }
        #pragma unroll
        for (int it = 0; it < NTL; ++it) {
            int node = it * 16 + n0;
            uint32_t w[4] = {0u, 0u, 0u, 0u};
            if (node < P) {
                int prev = (node == 0)     ? P - 1 : node - 1;
                int next = (node == P - 1) ? 0     : node + 1;
                float2 xp = *(const float2*)&xs[2 * prev];
                float2 xc = *(const float2*)&xs[2 * node];
                float2 xn = *(const float2*)&xs[2 * next];
                float ax = (xp.x + xc.x + xn.x) * (1.f / 3.f);
                float ay = (xp.y + xc.y + xn.y) * (1.f / 3.f);
                #pragma unroll
                for (int jj = 0; jj < 4; ++jj) {
                    float va = ax * w1x[2*jj]   + ay * w1y[2*jj]   + b1v[2*jj];
                    float vb = ax * w1x[2*jj+1] + ay * w1y[2*jj+1] + b1v[2*jj+1];
                    va = va > 0.f ? va : 0.f;
                    vb = vb > 0.f ? vb : 0.f;
                    w[jj] = pkbf2(va, vb);
                }
            }
            *(uint4*)&buf[(node * 16 + (kc1 ^ (node & 15))) * 8] =
                uint4{w[0], w[1], w[2], w[3]};
        }
    }
    __syncthreads();

    run_pass<0>(buf, g_wsw,             b2v, pool, tid);   // h1 -> h2 in place
    __syncthreads();
    run_pass<1>(buf, g_wsw + HID * HID, b3v, pool, tid);   // h2 -> pooled sums
    __syncthreads();

    // ---- FC head ----
    {
        int f = tid & 127, half = tid >> 7;
        float p = 0.f;
        const float* fw1c = fw1 + f;
        #pragma unroll 4
        for (int k = half * 64; k < half * 64 + 64; ++k)
            p += pool[k] * fw1c[k * 128];
        parts[half * 128 + f] = p;
    }
    __syncthreads();
    if (tid < 128) {
        float o1 = fb1[tid] + (parts[tid] + parts[128 + tid]) * (1.0f / 300.0f);
        s1[tid] = o1 > 0.f ? o1 : 0.f;
    }
    __syncthreads();
    if (tid < 128) {
        int o = tid >> 6, ln = tid & 63;
        float v = s1[ln] * fw2[ln * 2 + o] + s1[ln + 64] * fw2[(ln + 64) * 2 + o];
        #pragma unroll
        for (int off = 1; off <= 32; off <<= 1)
            v += __shfl_xor(v, off, 64);
        if (ln == 0) out[g * 2 + o] = v + fb2[o];
    }
}

extern "C" void kernel_launch(void* const* d_in, const int* in_sizes, int n_in,
                              void* d_out, int out_size, void* d_ws, size_t ws_size,
                              hipStream_t stream) {
    const float* x   = (const float*)d_in[0];
    const float* W1  = (const float*)d_in[3];
    const float* b1  = (const float*)d_in[4];
    const float* W2  = (const float*)d_in[5];
    const float* b2  = (const float*)d_in[6];
    const float* W3  = (const float*)d_in[7];
    const float* b3  = (const float*)d_in[8];
    const float* fw1 = (const float*)d_in[9];
    const float* fb1 = (const float*)d_in[10];
    const float* fw2 = (const float*)d_in[11];
    const float* fb2 = (const float*)d_in[12];
    float* out = (float*)d_out;

    k_prep <<<dim3(16), dim3(256), 0, stream>>>(W2, W3);
    k_graph<<<dim3(NG), dim3(256), 0, stream>>>(x, W1, b1, b2, b3,
                                                fw1, fb1, fw2, fb2, out);
}

// Round 9
// 125.815 us; speedup vs baseline: 1.1618x; 1.0338x over previous
//
#include <hip/hip_runtime.h>
#include <hip/hip_bf16.h>
#include <stdint.h>

#define P    300
#define HID  128
#define NG   1000
#define NTL  19          // 16-node tiles (304 rows, 300 valid)

typedef __attribute__((ext_vector_type(8))) short bf16x8;
typedef __attribute__((ext_vector_type(4))) short bf16x4;
typedef __attribute__((ext_vector_type(4))) float f32x4;

// Swizzled bf16 W^T, NATURAL feature order for both layers (the old W2
// permutation existed only to pair b32 stores across a wave's two
// ft-tiles; the 8-wave feature-split stores b16 per feature instead).
// chunk(fkey,kc) at slot fkey*16 + (kc ^ (fkey&15)).
__device__ short g_wsw[2 * HID * HID];

__device__ __forceinline__ short f2bf(float f) {
    union { float f; uint32_t u; } v; v.f = f;
    uint32_t r = v.u + 0x7fffu + ((v.u >> 16) & 1u);   // RNE
    return (short)(r >> 16);
}
__device__ __forceinline__ uint32_t pkbf2(float a, float b) {   // low=a, high=b
    union { __hip_bfloat162 h; uint32_t u; } cv;
    cv.h = __float22bfloat162_rn(float2{a, b});
    return cv.u;
}

// K=16 bf16 MFMA used as a cross-lane "selector": A is a constant 0/1
// matrix, B is a bf16-packed G-tile, C accumulates neighbor rows in f32.
// Layout match: C-frag of 16x16x32 (row=4q+reg, col=lm) == B-frag of
// 16x16x16 (k=4q+j, col=lm) -> pack is 2 pkbf2, NO shuffles.
__device__ __forceinline__ f32x4 mfma16(bf16x4 a, bf16x4 b, f32x4 c) {
#if __has_builtin(__builtin_amdgcn_mfma_f32_16x16x16bf16_1k)
    return __builtin_amdgcn_mfma_f32_16x16x16bf16_1k(a, b, c, 0, 0, 0);
#else
    asm("v_mfma_f32_16x16x16_bf16 %0, %1, %2, %0" : "+v"(c) : "v"(a), "v"(b));
    return c;
#endif
}

__global__ __launch_bounds__(256) void k_prep(const float* __restrict__ W2,
                                              const float* __restrict__ W3) {
    int b = blockIdx.x;                       // 16 blocks
    const float* W = (b < 8) ? W2 : W3;
    short* dst = g_wsw + ((b < 8) ? 0 : HID * HID);
    int t    = (b & 7) * 256 + threadIdx.x;   // 0..2047 chunks
    int fkey = t >> 4;
    int kc   = t & 15;
    bf16x8 o;
    #pragma unroll
    for (int j = 0; j < 8; ++j)
        o[j] = f2bf(W[(kc * 8 + j) * HID + fkey]);
    *(bf16x8*)&dst[(fkey * 16 + (kc ^ (fkey & 15))) * 8] = o;
}

// One GCN layer over one graph in LDS; 8 waves, wave wv owns ft-tile wv
// (16 features; feature-split doubles waves/CU vs the 4-wave 2-ft layout
// without duplicating ANY work -- rounds 4-7 showed every 4-wave variant
// pinned at VALUBusy ~50 / MfmaUtil ~20 from wave starvation at
// 2 waves/SIMD). Extra cost vs 4-wave: A-fragments read twice (~1 us of
// LDS BW per graph -- noise), b16 stores instead of paired b32.
// ROLLING-WINDOW schedule (round 7, race-proof: stores {2j-2,2j-1} vs
// reads {2j+1,2j+2} disjoint under per-iteration barrier) + selector-MFMA
// neighbor exchange (verified rounds 5-7, absmax unchanged):
//   Sb: row 4i <- row 4i-1, row 4i+3 <- row 4i+4 (in-tile)
//   Sp: row0 <- row15 of bP      Sn: row15 <- row0 of bN
//   Swa (tile18): row11 <- row0 of tile0 (node299.next = node0)
//   Swb (tile0):  row0 <- row11 of tile18 (node0.prev = node299;
//        Sp x bq18 adds row15 = node303 = 0 -- rows 300..303 stay zero)
template<int POOL>
__device__ __forceinline__ void run_pass(short* __restrict__ buf,
                                         const short* __restrict__ wbase,
                                         const float* __restrict__ bias,
                                         float* __restrict__ pool, int tid) {
    const int lane = tid & 63, wv = tid >> 6, q = lane >> 4, lm = lane & 15;
    const int fkey = wv * 16 + lm;            // this lane's feature (natural)
    bf16x8 wf[4];
    #pragma unroll
    for (int kk = 0; kk < 4; ++kk)
        wf[kk] = *(const bf16x8*)&wbase[(fkey * 16 + ((4 * kk + q) ^ lm)) * 8];
    const float biaf = bias[fkey];
    const int kcs = fkey >> 3, offs = fkey & 7;

    // constant selector A-fragments: A[m=lm][k=4q+j], entries bf16 1.0
    const short ONE = (short)0x3F80;
    bf16x4 Sb = {0, 0, 0, 0}, Sp = {0, 0, 0, 0}, Sn = {0, 0, 0, 0},
           Swa = {0, 0, 0, 0}, Swb = {0, 0, 0, 0};
    #pragma unroll
    for (int j = 0; j < 4; ++j) {
        const int k = 4 * q + j;
        if (((lm & 3) == 0 && k == lm - 1) || ((lm & 3) == 3 && k == lm + 1))
            Sb[j] = ONE;
        if (lm == 0  && k == 15) Sp[j]  = ONE;
        if (lm == 15 && k == 0 ) Sn[j]  = ONE;
        if (lm == 11 && k == 0 ) Swa[j] = ONE;
        if (lm == 0  && k == 11) Swb[j] = ONE;
    }

    float psum = 0.f;

    auto mfma_tile = [&](int t, f32x4 &G) {
        const short* tb = buf + t * 2048;
        G = f32x4{0.f, 0.f, 0.f, 0.f};
        #pragma unroll
        for (int kk = 0; kk < 4; ++kk) {
            bf16x8 af = *(const bf16x8*)&tb[(lm * 16 + ((4 * kk + q) ^ lm)) * 8];
            G = __builtin_amdgcn_mfma_f32_16x16x32_bf16(af, wf[kk], G, 0, 0, 0);
        }
    };
    auto pack = [&](const f32x4 &G, bf16x4 &d) {
        union { bf16x4 v; uint32_t u[2]; } pk;
        pk.u[0] = pkbf2(G[0], G[1]);
        pk.u[1] = pkbf2(G[2], G[3]);
        d = pk.v;
    };
    auto store_rows = [&](int T, float (&o)[4]) {
        #pragma unroll
        for (int i = 0; i < 4; ++i) {
            int node = T * 16 + q * 4 + i;
            buf[(node * 16 + (kcs ^ (node & 15))) * 8 + offs] = f2bf(o[i]);
        }
    };
    auto accum = [&](float (&o)[4]) { psum += o[0] + o[1] + o[2] + o[3]; };

    // epilogue: E f32 centers; bT/bP/bN packed self/prev/next; wrap:
    // 0 none, 1 tile18 (+Swa x bW), 2 tile0 (+Swb x bW).
    auto epi = [&](const f32x4 &E, const bf16x4 &bT, const bf16x4 &bP,
                   const bf16x4 &bN, int wrap, const bf16x4 &bW,
                   float (&o)[4]) {
        f32x4 C = {0.f, 0.f, 0.f, 0.f};
        C = mfma16(Sb, bT, C);
        C = mfma16(Sp, bP, C);
        C = mfma16(Sn, bN, C);
        if (wrap == 1) C = mfma16(Swa, bW, C);
        if (wrap == 2) C = mfma16(Swb, bW, C);
        const float s0 = E[0] + E[1];
        const float s2 = E[2] + E[3];
        float t0 = C[0] + s0;                // prev + G0 + G1
        float t1 = s0 + E[2];                // G0 + G1 + G2
        float t2 = E[1] + s2;                // G1 + G2 + G3
        float t3 = s2 + C[3];                // G2 + G3 + next
        float v0 = fmaf(t0, 1.f / 3.f, biaf);
        float v1 = fmaf(t1, 1.f / 3.f, biaf);
        float v2 = fmaf(t2, 1.f / 3.f, biaf);
        float v3 = fmaf(t3, 1.f / 3.f, biaf);
        o[0] = v0 > 0.f ? v0 : 0.f;
        o[1] = v1 > 0.f ? v1 : 0.f;
        o[2] = v2 > 0.f ? v2 : 0.f;
        o[3] = v3 > 0.f ? v3 : 0.f;
    };

    f32x4 G0c, Gp, Ga, Gb;
    bf16x4 bq0, bq1, bqA, bqB, bqC, bqD;

    // prologue: tile 0 (persist centers + pack; epilogued at tail)
    mfma_tile(0, G0c);
    pack(G0c, bq0);
    bqB = bq0;                // entering j=1: bqB = bq[0]
    bqA = bq0;                // unused at j=1 (init for safety)
    Gp = G0c;                 // unused at j=1

    for (int j = 1; j <= 9; ++j) {
        mfma_tile(2 * j - 1, Ga); pack(Ga, bqC);
        mfma_tile(2 * j,     Gb); pack(Gb, bqD);
        if (j == 1) bq1 = bqC;            // persist bq[1]
        if (!POOL) __syncthreads();       // all waves read tiles <= 2j
        if (j > 1) {                      // tile 2j-2 (tile 0 deferred)
            float o[4];
            epi(Gp, bqB, bqA, bqC, 0, bq0, o);
            if (POOL) accum(o); else store_rows(2 * j - 2, o);
        }
        {                                 // tile 2j-1
            float o[4];
            epi(Ga, bqC, bqB, bqD, 0, bq0, o);
            if (POOL) accum(o); else store_rows(2 * j - 1, o);
        }
        Gp = Gb; bqA = bqC; bqB = bqD;
    }

    // tail (all reads done): Gp = G[18], bqA = bq[17], bqB = bq[18]
    {
        float o18[4];   // rows 300..303 invalid: q==3 skipped
        epi(Gp, bqB, bqA, bq0, 1, bq0, o18);
        if (q < 3) { if (POOL) accum(o18); else store_rows(18, o18); }
        float o0[4];    // Sp x bq18 row15 = node303 = 0; Swb adds node299
        epi(G0c, bq0, bqB, bq1, 2, bqB, o0);
        if (POOL) accum(o0); else store_rows(0, o0);
    }

    if (POOL) {
        psum += __shfl_xor(psum, 16, 64);
        psum += __shfl_xor(psum, 32, 64);
        if (q == 0) pool[fkey] = psum;
    }
}

// One block (512 thr, 8 waves) per graph, feature-split. LDS 80384 B
// (HW-proven 2 blocks/CU across r0/r4/r7) -> 16 waves/CU = 4 waves/SIMD,
// double the 4-wave layout. launch_bounds cap model (r1/r2/r5/r6
// evidence): cap = 256/arg2 -> (512,1) caps at 256; live set ~80.
__global__ __launch_bounds__(512, 1) void k_graph(
        const float* __restrict__ x,
        const float* __restrict__ W1,  const float* __restrict__ b1,
        const float* __restrict__ b2v, const float* __restrict__ b3v,
        const float* __restrict__ fw1, const float* __restrict__ fb1,
        const float* __restrict__ fw2, const float* __restrict__ fb2,
        float* __restrict__ out) {
    __shared__ __align__(16) short buf[304 * HID];   // 77824 B, chunk-swizzled
    __shared__ __align__(16) float scr[640];         // 2560 B -> total 80384
    float* xs    = scr;          // 600 (layer-1 only)
    float* pool  = scr;          // 128
    float* parts = scr + 128;    // 256
    float* s1    = scr + 384;    // 128

    const int g = blockIdx.x, tid = threadIdx.x;

    if (tid < 150) *(float4*)&xs[tid * 4] = *(const float4*)&x[g * 600 + tid * 4];
    __syncthreads();

    // ---- layer 1: buf <- relu(avg3(x) @ W1 + b1); rows 300..303 zeroed ----
    {
        const int kc1 = tid & 15;
        const int n0  = tid >> 4;            // 0..31
        float w1x[8], w1y[8], b1v[8];
        #pragma unroll
        for (int j = 0; j < 8; ++j) {
            w1x[j] = W1[kc1 * 8 + j];
            w1y[j] = W1[HID + kc1 * 8 + j];
            b1v[j] = b1[kc1 * 8 + j];
        }
        #pragma unroll
        for (int it = 0; it < 10; ++it) {
            int node = it * 32 + n0;         // 0..319
            if (node < 304) {
                uint32_t w[4] = {0u, 0u, 0u, 0u};
                if (node < P) {
                    int prev = (node == 0)     ? P - 1 : node - 1;
                    int next = (node == P - 1) ? 0     : node + 1;
                    float2 xp = *(const float2*)&xs[2 * prev];
                    float2 xc = *(const float2*)&xs[2 * node];
                    float2 xn = *(const float2*)&xs[2 * next];
                    float ax = (xp.x + xc.x + xn.x) * (1.f / 3.f);
                    float ay = (xp.y + xc.y + xn.y) * (1.f / 3.f);
                    #pragma unroll
                    for (int jj = 0; jj < 4; ++jj) {
                        float va = ax * w1x[2*jj]   + ay * w1y[2*jj]   + b1v[2*jj];
                        float vb = ax * w1x[2*jj+1] + ay * w1y[2*jj+1] + b1v[2*jj+1];
                        va = va > 0.f ? va : 0.f;
                        vb = vb > 0.f ? vb : 0.f;
                        w[jj] = pkbf2(va, vb);
                    }
                }
                *(uint4*)&buf[(node * 16 + (kc1 ^ (node & 15))) * 8] =
                    uint4{w[0], w[1], w[2], w[3]};
            }
        }
    }
    __syncthreads();

    run_pass<0>(buf, g_wsw,             b2v, pool, tid);   // h1 -> h2 in place
    __syncthreads();
    run_pass<1>(buf, g_wsw + HID * HID, b3v, pool, tid);   // h2 -> pooled sums
    __syncthreads();

    // ---- FC head (tiny; 256 active threads) ----
    if (tid < 256) {
        int f = tid & 127, half = tid >> 7;
        float p = 0.f;
        const float* fw1c = fw1 + f;
        #pragma unroll 4
        for (int k = half * 64; k < half * 64 + 64; ++k)
            p += pool[k] * fw1c[k * 128];
        parts[half * 128 + f] = p;
    }
    __syncthreads();
    if (tid < 128) {
        float o1 = fb1[tid] + (parts[tid] + parts[128 + tid]) * (1.0f / 300.0f);
        s1[tid] = o1 > 0.f ? o1 : 0.f;
    }
    __syncthreads();
    if (tid < 128) {
        int o = tid >> 6, ln = tid & 63;
        float v = s1[ln] * fw2[ln * 2 + o] + s1[ln + 64] * fw2[(ln + 64) * 2 + o];
        #pragma unroll
        for (int off = 1; off <= 32; off <<= 1)
            v += __shfl_xor(v, off, 64);
        if (ln == 0) out[g * 2 + o] = v + fb2[o];
    }
}

extern "C" void kernel_launch(void* const* d_in, const int* in_sizes, int n_in,
                              void* d_out, int out_size, void* d_ws, size_t ws_size,
                              hipStream_t stream) {
    const float* x   = (const float*)d_in[0];
    const float* W1  = (const float*)d_in[3];
    const float* b1  = (const float*)d_in[4];
    const float* W2  = (const float*)d_in[5];
    const float* b2  = (const float*)d_in[6];
    const float* W3  = (const float*)d_in[7];
    const float* b3  = (const float*)d_in[8];
    const float* fw1 = (const float*)d_in[9];
    const float* fb1 = (const float*)d_in[10];
    const float* fw2 = (const float*)d_in[11];
    const float* fb2 = (const float*)d_in[12];
    float* out = (float*)d_out;

    k_prep <<<dim3(16), dim3(256), 0, stream>>>(W2, W3);
    k_graph<<<dim3(NG), dim3(512), 0, stream>>>(x, W1, b1, b2, b3,
                                                fw1, fb1, fw2, fb2, out);
}